// Round 8
// baseline (683.905 us; speedup 1.0000x reference)
//
#include <hip/hip_runtime.h>

#define NPTS 65536
#define CC 16
#define PH 128
#define SW 256
#define MB 64    // points per subnet block
#define SP 264   // LDS row stride in halves (528 B, 16B-aligned)

typedef _Float16 half8 __attribute__((ext_vector_type(8)));
typedef _Float16 half4 __attribute__((ext_vector_type(4)));
typedef _Float16 half2 __attribute__((ext_vector_type(2)));
typedef float float4_ __attribute__((ext_vector_type(4)));
typedef float float2_ __attribute__((ext_vector_type(2)));

// tanh(x) = 1 - 2*rcp(exp2(2x*log2e)+1); v_rcp_f32 (1ulp) not IEEE fdiv.
__device__ __forceinline__ float fast_tanh(float x) {
    float e = __builtin_amdgcn_exp2f(x * 2.8853900817779268f);
    float r = __builtin_amdgcn_rcpf(e + 1.0f);
    return fmaf(-2.0f, r, 1.0f);
}

__device__ __forceinline__ half4 pack4(float a, float b, float c, float d) {
    half2 lo = __builtin_bit_cast(half2, __builtin_amdgcn_cvt_pkrtz(a, b));
    half2 hi = __builtin_bit_cast(half2, __builtin_amdgcn_cvt_pkrtz(c, d));
    half4 h;
    h[0] = lo[0]; h[1] = lo[1]; h[2] = hi[0]; h[3] = hi[1];
    return h;
}

// ---- kernel 1: transpose+convert sub_Wmid [cl][w][v] f32 -> Wt [cl][v][w] f16
__global__ __launch_bounds__(256) void prep_wt(const float* __restrict__ Wmid,
                                               _Float16* __restrict__ Wt) {
    __shared__ float T[64][65];
    int b = blockIdx.x;      // b = cl*16 + tile
    int cl = b >> 4;
    int tile = b & 15;
    int w0 = (tile >> 2) * 64, v0 = (tile & 3) * 64;
    int t = threadIdx.x;
    int col = t & 63, row4 = t >> 6;
    const float* src = Wmid + ((size_t)cl << 16);
#pragma unroll
    for (int rr = 0; rr < 16; ++rr) {
        int wl = rr * 4 + row4;
        T[wl][col] = src[(size_t)(w0 + wl) * 256 + v0 + col];
    }
    __syncthreads();
    _Float16* dst = Wt + ((size_t)cl << 16);
#pragma unroll
    for (int rr = 0; rr < 16; ++rr) {
        int v = rr * 4 + row4;
        dst[(size_t)(v0 + v) * 256 + w0 + col] = (_Float16)T[col][v];
    }
}

// ---- kernel 2: PoU gating net (fp32) -> wgt[n][c] ----
__global__ __launch_bounds__(256) void pou_kernel(
    const float* __restrict__ x, const float* __restrict__ W0,
    const float* __restrict__ b0, const float* __restrict__ Wmid,
    const float* __restrict__ bmid, const float* __restrict__ Wl,
    const float* __restrict__ bl, float* __restrict__ wgt) {
    __shared__ float hA[64][PH + 1];
    int t = threadIdx.x;
    int p = t & 63;
    int g4 = __builtin_amdgcn_readfirstlane(t >> 6);
    int jb = g4 * 32;
    int n0 = blockIdx.x * 64;
    float x0 = x[(size_t)(n0 + p) * 2];
    float x1 = x[(size_t)(n0 + p) * 2 + 1];

#pragma unroll
    for (int jj = 0; jj < 32; ++jj) {
        int j = jb + jj;
        float a = x0 * W0[j] + x1 * W0[PH + j] + b0[j];
        hA[p][j] = a > 0.f ? a : 0.f;
    }
    __syncthreads();

    for (int l = 0; l < 2; ++l) {
        float acc[32];
#pragma unroll
        for (int jj = 0; jj < 32; ++jj) acc[jj] = bmid[l * PH + jb + jj];
        for (int k = 0; k < PH; ++k) {
            float hv = hA[p][k];
#pragma unroll
            for (int jj = 0; jj < 32; ++jj)
                acc[jj] += hv * Wmid[(l * PH + k) * PH + jb + jj];
        }
        float resv[32];
#pragma unroll
        for (int jj = 0; jj < 32; ++jj) resv[jj] = hA[p][jb + jj];
        __syncthreads();
#pragma unroll
        for (int jj = 0; jj < 32; ++jj) {
            float r = acc[jj] > 0.f ? acc[jj] : 0.f;
            hA[p][jb + jj] = resv[jj] + r;
        }
        __syncthreads();
    }

    int c4 = g4 * 4;
    float lacc[4];
#pragma unroll
    for (int cc = 0; cc < 4; ++cc) lacc[cc] = bl[c4 + cc];
    for (int k = 0; k < PH; ++k) {
        float hv = hA[p][k];
#pragma unroll
        for (int cc = 0; cc < 4; ++cc) lacc[cc] += hv * Wl[k * CC + c4 + cc];
    }
    __syncthreads();
#pragma unroll
    for (int cc = 0; cc < 4; ++cc) hA[p][c4 + cc] = lacc[cc];
    __syncthreads();

    if (t < 64) {
        float lg[CC];
#pragma unroll
        for (int c = 0; c < CC; ++c) lg[c] = hA[t][c];
        float m = lg[0];
#pragma unroll
        for (int c = 1; c < CC; ++c) m = fmaxf(m, lg[c]);
        float s = 0.f;
#pragma unroll
        for (int c = 0; c < CC; ++c) {
            lg[c] = __builtin_amdgcn_exp2f((lg[c] - m) * 1.4426950408889634f);
            s += lg[c];
        }
        float inv = 1.0f / s;
        float* wr = wgt + (size_t)(n0 + t) * CC;
#pragma unroll
        for (int c = 0; c < CC; ++c) wr[c] = lg[c] * inv;
    }
}

// ---- kernel 3: batched subnets (f16 MFMA) -> u[c][n] ----
// MB=64: 4 waves; wave w owns neurons [w*64,+64) x all 64 points.
// launch_bounds(256,3): ~170-reg unified budget so acc (64 AGPR) + A-prefetch
// double-buffer fits WITHOUT spill (R6 spilled at the (256,4)/128 budget).
// Layer-2 u-dot fused in registers (fp32), quad-reduced via shfl.
__global__ __launch_bounds__(256, 3) void subnet_kernel(
    const float* __restrict__ x, const float* __restrict__ centers,
    const float* __restrict__ scales, const float* __restrict__ W0,
    const float* __restrict__ b0, const _Float16* __restrict__ Wt,
    const float* __restrict__ bmid, const float* __restrict__ Wl,
    const float* __restrict__ bl, float* __restrict__ u) {
    __shared__ _Float16 g[MB * SP];
    __shared__ float xs[MB][2];
    __shared__ float part[4][MB];
    int t = threadIdx.x;
    int c = blockIdx.y;
    int n0 = blockIdx.x * MB;

    if (t < MB) {
        float xx0 = x[(size_t)(n0 + t) * 2];
        float xx1 = x[(size_t)(n0 + t) * 2 + 1];
        xs[t][0] = (xx0 - centers[c * 2]) / scales[c * 2];
        xs[t][1] = (xx1 - centers[c * 2 + 1]) / scales[c * 2 + 1];
    }
    __syncthreads();

    // layer 0: thread owns 4 consecutive neurons x 16 points
    {
        int ln = t & 63;          // neuron quad: neurons ln*4..ln*4+3
        int pb = (t >> 6) * 16;   // 16 points
        const float* W0c = W0 + (size_t)c * 2 * SW;
        float4_ w0 = *(const float4_*)&W0c[ln * 4];
        float4_ w1 = *(const float4_*)&W0c[SW + ln * 4];
        float4_ bb = *(const float4_*)&b0[c * SW + ln * 4];
#pragma unroll 4
        for (int p = 0; p < 16; ++p) {
            float2_ xv = *(const float2_*)&xs[pb + p][0];
            float tv[4];
#pragma unroll
            for (int j = 0; j < 4; ++j)
                tv[j] = fast_tanh(fmaf(xv[0], w0[j], fmaf(xv[1], w1[j], bb[j])));
            *(half4*)&g[(pb + p) * SP + ln * 4] = pack4(tv[0], tv[1], tv[2], tv[3]);
        }
    }
    __syncthreads();

    int lane = t & 63;
    int wave = t >> 6;
    int quad = lane >> 4;
    int l16 = lane & 15;
    int mb = wave * 64;  // this wave's 64-neuron strip

    // ---- layer 1: MFMA (A prefetched) + tanh epilogue back to g ----
    {
        const _Float16* Wp = Wt + (((size_t)(c * 2 + 0)) << 16);
        const _Float16* Arow = Wp + (mb + l16) * SW + quad * 8;
        // hoist bias load so its latency hides under the MFMA loop
        const float* bp = bmid + (c * 2 + 0) * SW + mb + quad * 4;
        float4_ bias[4];
#pragma unroll
        for (int mt = 0; mt < 4; ++mt) bias[mt] = *(const float4_*)&bp[mt * 16];
        float4_ acc[4][4] = {};
        half8 abuf[2][4];
#pragma unroll
        for (int mt = 0; mt < 4; ++mt)
            abuf[0][mt] = *(const half8*)&Arow[mt * 16 * SW];
#pragma unroll
        for (int kt = 0; kt < 8; ++kt) {
            int cur = kt & 1, nxt = cur ^ 1;
            if (kt < 7) {
#pragma unroll
                for (int mt = 0; mt < 4; ++mt)
                    abuf[nxt][mt] =
                        *(const half8*)&Arow[mt * 16 * SW + (kt + 1) * 32];
            }
            half8 b[4];
#pragma unroll
            for (int nt = 0; nt < 4; ++nt)
                b[nt] = *(const half8*)&g[(nt * 16 + l16) * SP + kt * 32 + quad * 8];
#pragma unroll
            for (int mt = 0; mt < 4; ++mt)
#pragma unroll
                for (int nt = 0; nt < 4; ++nt)
                    acc[mt][nt] = __builtin_amdgcn_mfma_f32_16x16x32_f16(
                        abuf[cur][mt], b[nt], acc[mt][nt], 0, 0, 0);
        }
        __syncthreads();  // all waves done READING g
#pragma unroll
        for (int mt = 0; mt < 4; ++mt) {
#pragma unroll
            for (int nt = 0; nt < 4; ++nt) {
                float t0 = fast_tanh(acc[mt][nt][0] + bias[mt][0]);
                float t1 = fast_tanh(acc[mt][nt][1] + bias[mt][1]);
                float t2 = fast_tanh(acc[mt][nt][2] + bias[mt][2]);
                float t3 = fast_tanh(acc[mt][nt][3] + bias[mt][3]);
                *(half4*)&g[(nt * 16 + l16) * SP + mb + mt * 16 + quad * 4] =
                    pack4(t0, t1, t2, t3);
            }
        }
        __syncthreads();
    }

    // ---- layer 2: MFMA (A prefetched) + fused tanh*Wl dot ----
    {
        const _Float16* Wp = Wt + (((size_t)(c * 2 + 1)) << 16);
        const _Float16* Arow = Wp + (mb + l16) * SW + quad * 8;
        const float* bp = bmid + (c * 2 + 1) * SW + mb + quad * 4;
        const float* wlp = Wl + c * SW + mb + quad * 4;
        float4_ bias[4], wv[4];
#pragma unroll
        for (int mt = 0; mt < 4; ++mt) {
            bias[mt] = *(const float4_*)&bp[mt * 16];
            wv[mt] = *(const float4_*)&wlp[mt * 16];
        }
        float4_ acc[4][4] = {};
        half8 abuf[2][4];
#pragma unroll
        for (int mt = 0; mt < 4; ++mt)
            abuf[0][mt] = *(const half8*)&Arow[mt * 16 * SW];
#pragma unroll
        for (int kt = 0; kt < 8; ++kt) {
            int cur = kt & 1, nxt = cur ^ 1;
            if (kt < 7) {
#pragma unroll
                for (int mt = 0; mt < 4; ++mt)
                    abuf[nxt][mt] =
                        *(const half8*)&Arow[mt * 16 * SW + (kt + 1) * 32];
            }
            half8 b[4];
#pragma unroll
            for (int nt = 0; nt < 4; ++nt)
                b[nt] = *(const half8*)&g[(nt * 16 + l16) * SP + kt * 32 + quad * 8];
#pragma unroll
            for (int mt = 0; mt < 4; ++mt)
#pragma unroll
                for (int nt = 0; nt < 4; ++nt)
                    acc[mt][nt] = __builtin_amdgcn_mfma_f32_16x16x32_f16(
                        abuf[cur][mt], b[nt], acc[mt][nt], 0, 0, 0);
        }
        float s[4] = {0.f, 0.f, 0.f, 0.f};
#pragma unroll
        for (int mt = 0; mt < 4; ++mt) {
#pragma unroll
            for (int nt = 0; nt < 4; ++nt) {
                float t0 = fast_tanh(acc[mt][nt][0] + bias[mt][0]);
                float t1 = fast_tanh(acc[mt][nt][1] + bias[mt][1]);
                float t2 = fast_tanh(acc[mt][nt][2] + bias[mt][2]);
                float t3 = fast_tanh(acc[mt][nt][3] + bias[mt][3]);
                s[nt] += fmaf(t0, wv[mt][0],
                          fmaf(t1, wv[mt][1],
                               fmaf(t2, wv[mt][2], t3 * wv[mt][3])));
            }
        }
        // reduce over quads (lanes l16, l16+16, l16+32, l16+48)
#pragma unroll
        for (int nt = 0; nt < 4; ++nt) {
            s[nt] += __shfl_xor(s[nt], 16);
            s[nt] += __shfl_xor(s[nt], 32);
        }
        if (quad == 0) {
#pragma unroll
            for (int nt = 0; nt < 4; ++nt) part[wave][nt * 16 + l16] = s[nt];
        }
    }
    __syncthreads();
    if (t < MB) {
        float s = part[0][t] + part[1][t] + part[2][t] + part[3][t] + bl[c];
        u[(size_t)c * NPTS + n0 + t] = s;
    }
}

// ---- kernel 4: windowed sum + hard BC ansatz ----
__global__ __launch_bounds__(256) void final_kernel(const float* __restrict__ x,
                                                    const float* __restrict__ wgt,
                                                    const float* __restrict__ u,
                                                    float* __restrict__ out) {
    int n = blockIdx.x * 256 + threadIdx.x;
    const float* wr = wgt + (size_t)n * CC;
    float s = 0.f;
#pragma unroll
    for (int c = 0; c < CC; ++c) s += wr[c] * u[(size_t)c * NPTS + n];
    float x0 = x[(size_t)n * 2], x1 = x[(size_t)n * 2 + 1];
    out[n] = s * (x0 * (1.f - x0)) * (x1 * (1.f - x1));
}

extern "C" void kernel_launch(void* const* d_in, const int* in_sizes, int n_in,
                              void* d_out, int out_size, void* d_ws, size_t ws_size,
                              hipStream_t stream) {
    const float* x = (const float*)d_in[0];
    const float* centers = (const float*)d_in[1];
    const float* scales = (const float*)d_in[2];
    const float* pou_W0 = (const float*)d_in[3];
    const float* pou_b0 = (const float*)d_in[4];
    const float* pou_Wmid = (const float*)d_in[5];
    const float* pou_bmid = (const float*)d_in[6];
    const float* pou_Wl = (const float*)d_in[7];
    const float* pou_bl = (const float*)d_in[8];
    const float* sub_W0 = (const float*)d_in[9];
    const float* sub_b0 = (const float*)d_in[10];
    const float* sub_Wmid = (const float*)d_in[11];
    const float* sub_bmid = (const float*)d_in[12];
    const float* sub_Wl = (const float*)d_in[13];
    const float* sub_bl = (const float*)d_in[14];
    float* out = (float*)d_out;

    _Float16* wt = (_Float16*)d_ws;                         // 4 MB
    float* wgt = (float*)((char*)d_ws + (4u << 20));        // 4 MB
    float* u = (float*)((char*)d_ws + (8u << 20));          // 4 MB

    prep_wt<<<dim3(512), dim3(256), 0, stream>>>(sub_Wmid, wt);
    pou_kernel<<<dim3(NPTS / 64), dim3(256), 0, stream>>>(
        x, pou_W0, pou_b0, pou_Wmid, pou_bmid, pou_Wl, pou_bl, wgt);
    subnet_kernel<<<dim3(NPTS / MB, CC), dim3(256), 0, stream>>>(
        x, centers, scales, sub_W0, sub_b0, wt, sub_bmid, sub_Wl, sub_bl, u);
    final_kernel<<<dim3(NPTS / 256), dim3(256), 0, stream>>>(x, wgt, u, out);
}

// Round 9
// 644.382 us; speedup vs baseline: 1.0613x; 1.0613x over previous
//
#include <hip/hip_runtime.h>

#define NPTS 65536
#define CC 16
#define PH 128
#define SW 256
#define MB 64    // points per subnet block
#define SP 264   // LDS row stride in halves (528 B, 16B-aligned)

typedef _Float16 half8 __attribute__((ext_vector_type(8)));
typedef _Float16 half4 __attribute__((ext_vector_type(4)));
typedef _Float16 half2 __attribute__((ext_vector_type(2)));
typedef float float4_ __attribute__((ext_vector_type(4)));
typedef float float2_ __attribute__((ext_vector_type(2)));

// tanh(x) = 1 - 2*rcp(exp2(2x*log2e)+1); v_rcp_f32 (1ulp) not IEEE fdiv.
__device__ __forceinline__ float fast_tanh(float x) {
    float e = __builtin_amdgcn_exp2f(x * 2.8853900817779268f);
    float r = __builtin_amdgcn_rcpf(e + 1.0f);
    return fmaf(-2.0f, r, 1.0f);
}

__device__ __forceinline__ half4 pack4(float a, float b, float c, float d) {
    half2 lo = __builtin_bit_cast(half2, __builtin_amdgcn_cvt_pkrtz(a, b));
    half2 hi = __builtin_bit_cast(half2, __builtin_amdgcn_cvt_pkrtz(c, d));
    half4 h;
    h[0] = lo[0]; h[1] = lo[1]; h[2] = hi[0]; h[3] = hi[1];
    return h;
}

// ---- kernel 1: transpose+convert sub_Wmid [cl][w][v] f32 -> Wt [cl][v][w] f16
__global__ __launch_bounds__(256) void prep_wt(const float* __restrict__ Wmid,
                                               _Float16* __restrict__ Wt) {
    __shared__ float T[64][65];
    int b = blockIdx.x;      // b = cl*16 + tile
    int cl = b >> 4;
    int tile = b & 15;
    int w0 = (tile >> 2) * 64, v0 = (tile & 3) * 64;
    int t = threadIdx.x;
    int col = t & 63, row4 = t >> 6;
    const float* src = Wmid + ((size_t)cl << 16);
#pragma unroll
    for (int rr = 0; rr < 16; ++rr) {
        int wl = rr * 4 + row4;
        T[wl][col] = src[(size_t)(w0 + wl) * 256 + v0 + col];
    }
    __syncthreads();
    _Float16* dst = Wt + ((size_t)cl << 16);
#pragma unroll
    for (int rr = 0; rr < 16; ++rr) {
        int v = rr * 4 + row4;
        dst[(size_t)(v0 + v) * 256 + w0 + col] = (_Float16)T[col][v];
    }
}

// ---- kernel 2: PoU gating net (fp32) -> wgtT[c][n] (transposed for subnet) --
__global__ __launch_bounds__(256) void pou_kernel(
    const float* __restrict__ x, const float* __restrict__ W0,
    const float* __restrict__ b0, const float* __restrict__ Wmid,
    const float* __restrict__ bmid, const float* __restrict__ Wl,
    const float* __restrict__ bl, float* __restrict__ wgtT) {
    __shared__ float hA[64][PH + 1];
    int t = threadIdx.x;
    int p = t & 63;
    int g4 = __builtin_amdgcn_readfirstlane(t >> 6);
    int jb = g4 * 32;
    int n0 = blockIdx.x * 64;
    float x0 = x[(size_t)(n0 + p) * 2];
    float x1 = x[(size_t)(n0 + p) * 2 + 1];

#pragma unroll
    for (int jj = 0; jj < 32; ++jj) {
        int j = jb + jj;
        float a = x0 * W0[j] + x1 * W0[PH + j] + b0[j];
        hA[p][j] = a > 0.f ? a : 0.f;
    }
    __syncthreads();

    for (int l = 0; l < 2; ++l) {
        float acc[32];
#pragma unroll
        for (int jj = 0; jj < 32; ++jj) acc[jj] = bmid[l * PH + jb + jj];
        for (int k = 0; k < PH; ++k) {
            float hv = hA[p][k];
#pragma unroll
            for (int jj = 0; jj < 32; ++jj)
                acc[jj] += hv * Wmid[(l * PH + k) * PH + jb + jj];
        }
        float resv[32];
#pragma unroll
        for (int jj = 0; jj < 32; ++jj) resv[jj] = hA[p][jb + jj];
        __syncthreads();
#pragma unroll
        for (int jj = 0; jj < 32; ++jj) {
            float r = acc[jj] > 0.f ? acc[jj] : 0.f;
            hA[p][jb + jj] = resv[jj] + r;
        }
        __syncthreads();
    }

    int c4 = g4 * 4;
    float lacc[4];
#pragma unroll
    for (int cc = 0; cc < 4; ++cc) lacc[cc] = bl[c4 + cc];
    for (int k = 0; k < PH; ++k) {
        float hv = hA[p][k];
#pragma unroll
        for (int cc = 0; cc < 4; ++cc) lacc[cc] += hv * Wl[k * CC + c4 + cc];
    }
    __syncthreads();
#pragma unroll
    for (int cc = 0; cc < 4; ++cc) hA[p][c4 + cc] = lacc[cc];
    __syncthreads();

    if (t < 64) {
        float lg[CC];
#pragma unroll
        for (int c = 0; c < CC; ++c) lg[c] = hA[t][c];
        float m = lg[0];
#pragma unroll
        for (int c = 1; c < CC; ++c) m = fmaxf(m, lg[c]);
        float s = 0.f;
#pragma unroll
        for (int c = 0; c < CC; ++c) {
            lg[c] = __builtin_amdgcn_exp2f((lg[c] - m) * 1.4426950408889634f);
            s += lg[c];
        }
        float inv = 1.0f / s;
        // transposed store: wgtT[c][n] -> coalesced read in subnet
#pragma unroll
        for (int c = 0; c < CC; ++c)
            wgtT[(size_t)c * NPTS + n0 + t] = lg[c] * inv;
    }
}

// ---- kernel 3: batched subnets (f16 MFMA) -> atomicAdd into out ----
// MB=64: 4 waves; wave w owns neurons [w*64,+64) x all 64 points.
// Bias folded into MFMA C-operand (acc init). Layer-2 u-dot fused in
// registers; windowed sum + ansatz fused via atomicAdd (out pre-zeroed).
__global__ __launch_bounds__(256, 4) void subnet_kernel(
    const float* __restrict__ x, const float* __restrict__ centers,
    const float* __restrict__ scales, const float* __restrict__ W0,
    const float* __restrict__ b0, const _Float16* __restrict__ Wt,
    const float* __restrict__ bmid, const float* __restrict__ Wl,
    const float* __restrict__ bl, const float* __restrict__ wgtT,
    float* __restrict__ out) {
    __shared__ _Float16 g[MB * SP];
    __shared__ float part[4][MB];
    int t = threadIdx.x;
    int c = blockIdx.y;
    int n0 = blockIdx.x * MB;

    // layer 0: thread owns 4 consecutive neurons x 16 points; x loads are
    // wave-uniform (L1 broadcast); scales are exact pow2 so rcp-mul is exact
    {
        float cx0 = centers[c * 2], cx1 = centers[c * 2 + 1];
        float is0 = 1.0f / scales[c * 2], is1 = 1.0f / scales[c * 2 + 1];
        int ln = t & 63;          // neuron quad: neurons ln*4..ln*4+3
        int pb = (t >> 6) * 16;   // 16 points
        const float* W0c = W0 + (size_t)c * 2 * SW;
        float4_ w0 = *(const float4_*)&W0c[ln * 4];
        float4_ w1 = *(const float4_*)&W0c[SW + ln * 4];
        float4_ bb = *(const float4_*)&b0[c * SW + ln * 4];
#pragma unroll 4
        for (int p = 0; p < 16; ++p) {
            float2_ xv = *(const float2_*)&x[(size_t)(n0 + pb + p) * 2];
            float xn0 = (xv[0] - cx0) * is0;
            float xn1 = (xv[1] - cx1) * is1;
            float tv[4];
#pragma unroll
            for (int j = 0; j < 4; ++j)
                tv[j] = fast_tanh(fmaf(xn0, w0[j], fmaf(xn1, w1[j], bb[j])));
            *(half4*)&g[(pb + p) * SP + ln * 4] = pack4(tv[0], tv[1], tv[2], tv[3]);
        }
    }
    __syncthreads();

    int lane = t & 63;
    int wave = t >> 6;
    int quad = lane >> 4;
    int l16 = lane & 15;
    int mb = wave * 64;  // this wave's 64-neuron strip

    // ---- layer 1: MFMA (bias in C) + tanh epilogue back to g ----
    {
        const _Float16* Wp = Wt + (((size_t)(c * 2 + 0)) << 16);
        const _Float16* Arow = Wp + (mb + l16) * SW + quad * 8;
        const float* bp = bmid + (c * 2 + 0) * SW + mb + quad * 4;
        float4_ acc[4][4];
#pragma unroll
        for (int mt = 0; mt < 4; ++mt) {
            float4_ bv = *(const float4_*)&bp[mt * 16];
#pragma unroll
            for (int nt = 0; nt < 4; ++nt) acc[mt][nt] = bv;
        }
#pragma unroll
        for (int kt = 0; kt < 8; ++kt) {
            half8 a[4], b[4];
#pragma unroll
            for (int mt = 0; mt < 4; ++mt)
                a[mt] = *(const half8*)&Arow[mt * 16 * SW + kt * 32];
#pragma unroll
            for (int nt = 0; nt < 4; ++nt)
                b[nt] = *(const half8*)&g[(nt * 16 + l16) * SP + kt * 32 + quad * 8];
#pragma unroll
            for (int mt = 0; mt < 4; ++mt)
#pragma unroll
                for (int nt = 0; nt < 4; ++nt)
                    acc[mt][nt] = __builtin_amdgcn_mfma_f32_16x16x32_f16(
                        a[mt], b[nt], acc[mt][nt], 0, 0, 0);
        }
        __syncthreads();  // all waves done READING g
#pragma unroll
        for (int mt = 0; mt < 4; ++mt) {
#pragma unroll
            for (int nt = 0; nt < 4; ++nt) {
                float t0 = fast_tanh(acc[mt][nt][0]);
                float t1 = fast_tanh(acc[mt][nt][1]);
                float t2 = fast_tanh(acc[mt][nt][2]);
                float t3 = fast_tanh(acc[mt][nt][3]);
                *(half4*)&g[(nt * 16 + l16) * SP + mb + mt * 16 + quad * 4] =
                    pack4(t0, t1, t2, t3);
            }
        }
        __syncthreads();
    }

    // ---- layer 2: MFMA (bias in C) + fused tanh*Wl dot ----
    {
        const _Float16* Wp = Wt + (((size_t)(c * 2 + 1)) << 16);
        const _Float16* Arow = Wp + (mb + l16) * SW + quad * 8;
        const float* bp = bmid + (c * 2 + 1) * SW + mb + quad * 4;
        float4_ acc[4][4];
#pragma unroll
        for (int mt = 0; mt < 4; ++mt) {
            float4_ bv = *(const float4_*)&bp[mt * 16];
#pragma unroll
            for (int nt = 0; nt < 4; ++nt) acc[mt][nt] = bv;
        }
#pragma unroll
        for (int kt = 0; kt < 8; ++kt) {
            half8 a[4], b[4];
#pragma unroll
            for (int mt = 0; mt < 4; ++mt)
                a[mt] = *(const half8*)&Arow[mt * 16 * SW + kt * 32];
#pragma unroll
            for (int nt = 0; nt < 4; ++nt)
                b[nt] = *(const half8*)&g[(nt * 16 + l16) * SP + kt * 32 + quad * 8];
#pragma unroll
            for (int mt = 0; mt < 4; ++mt)
#pragma unroll
                for (int nt = 0; nt < 4; ++nt)
                    acc[mt][nt] = __builtin_amdgcn_mfma_f32_16x16x32_f16(
                        a[mt], b[nt], acc[mt][nt], 0, 0, 0);
        }
        const float* wlp = Wl + c * SW + mb + quad * 4;
        float s[4] = {0.f, 0.f, 0.f, 0.f};
#pragma unroll
        for (int mt = 0; mt < 4; ++mt) {
            float4_ wv = *(const float4_*)&wlp[mt * 16];
#pragma unroll
            for (int nt = 0; nt < 4; ++nt) {
                float t0 = fast_tanh(acc[mt][nt][0]);
                float t1 = fast_tanh(acc[mt][nt][1]);
                float t2 = fast_tanh(acc[mt][nt][2]);
                float t3 = fast_tanh(acc[mt][nt][3]);
                s[nt] += fmaf(t0, wv[0],
                          fmaf(t1, wv[1], fmaf(t2, wv[2], t3 * wv[3])));
            }
        }
        // reduce over quads (lanes l16, l16+16, l16+32, l16+48)
#pragma unroll
        for (int nt = 0; nt < 4; ++nt) {
            s[nt] += __shfl_xor(s[nt], 16);
            s[nt] += __shfl_xor(s[nt], 32);
        }
        if (quad == 0) {
#pragma unroll
            for (int nt = 0; nt < 4; ++nt) part[wave][nt * 16 + l16] = s[nt];
        }
    }
    __syncthreads();
    if (t < MB) {
        int n = n0 + t;
        float uv = part[0][t] + part[1][t] + part[2][t] + part[3][t] + bl[c];
        float w = wgtT[(size_t)c * NPTS + n];
        float2_ xv = *(const float2_*)&x[(size_t)n * 2];
        float ans = (xv[0] * (1.f - xv[0])) * (xv[1] * (1.f - xv[1]));
        atomicAdd(&out[n], uv * w * ans);
    }
}

extern "C" void kernel_launch(void* const* d_in, const int* in_sizes, int n_in,
                              void* d_out, int out_size, void* d_ws, size_t ws_size,
                              hipStream_t stream) {
    const float* x = (const float*)d_in[0];
    const float* centers = (const float*)d_in[1];
    const float* scales = (const float*)d_in[2];
    const float* pou_W0 = (const float*)d_in[3];
    const float* pou_b0 = (const float*)d_in[4];
    const float* pou_Wmid = (const float*)d_in[5];
    const float* pou_bmid = (const float*)d_in[6];
    const float* pou_Wl = (const float*)d_in[7];
    const float* pou_bl = (const float*)d_in[8];
    const float* sub_W0 = (const float*)d_in[9];
    const float* sub_b0 = (const float*)d_in[10];
    const float* sub_Wmid = (const float*)d_in[11];
    const float* sub_bmid = (const float*)d_in[12];
    const float* sub_Wl = (const float*)d_in[13];
    const float* sub_bl = (const float*)d_in[14];
    float* out = (float*)d_out;

    _Float16* wt = (_Float16*)d_ws;                         // 4 MB
    float* wgtT = (float*)((char*)d_ws + (4u << 20));       // 4 MB

    hipMemsetAsync(out, 0, (size_t)out_size * sizeof(float), stream);
    prep_wt<<<dim3(512), dim3(256), 0, stream>>>(sub_Wmid, wt);
    pou_kernel<<<dim3(NPTS / 64), dim3(256), 0, stream>>>(
        x, pou_W0, pou_b0, pou_Wmid, pou_bmid, pou_Wl, pou_bl, wgtT);
    subnet_kernel<<<dim3(NPTS / MB, CC), dim3(256), 0, stream>>>(
        x, centers, scales, sub_W0, sub_b0, wt, sub_bmid, sub_Wl, sub_bl,
        wgtT, out);
}